// Round 8
// baseline (856.798 us; speedup 1.0000x reference)
//
#include <hip/hip_runtime.h>

#define NN 50000            // nodes
#define NE 800000           // edges
#define NF 128              // input features
#define NH 64               // hidden
#define NG 256              // graphs
#define NC 196              // chunks: ceil(NE/CH)
#define CH 4096             // edges per partition chunk
#define NBK 391             // buckets of 128 dst nodes: ceil(NN/128)
#define NBA 392             // histg bucket stride (padded)
#define CELL 40             // per-(chunk,bucket) capacity (packed 4B entries)
#define ECAP 2560           // per-bucket edge capacity (LDS stage)
#define NG1 391             // gemm1 blocks (128 rows each)
#define NG2 782             // gemm2 blocks (64 rows each)

typedef __attribute__((ext_vector_type(8))) short bf16x8;
typedef __attribute__((ext_vector_type(4))) float f32x4;

static __device__ __forceinline__ unsigned short f2bf(float f) {
    union { float f; unsigned u; } v; v.f = f;
    unsigned r = v.u + 0x7FFF + ((v.u >> 16) & 1);   // RNE
    return (unsigned short)(r >> 16);
}
static __device__ __forceinline__ float lo16(unsigned u) {
    return __uint_as_float(u << 16);
}
static __device__ __forceinline__ float hi16(unsigned u) {
    return __uint_as_float(u & 0xFFFF0000u);
}
static __device__ __forceinline__ unsigned pack2(float a, float b) {
    return (unsigned)f2bf(a) | ((unsigned)f2bf(b) << 16);
}

// ---------------------------------------------------------------- K0: zero deg/psum/cnt + pack W2
__global__ __launch_bounds__(256) void zero_init(int* __restrict__ deg,
                                                 float* __restrict__ psum,
                                                 const float* __restrict__ W2,
                                                 unsigned* __restrict__ W2p) {
    const int t = threadIdx.x, b = blockIdx.x;
    if (b < 49) {                                   // 49*256 int4 = 50176 ints exactly
        ((int4*)deg)[b * 256 + t] = make_int4(0, 0, 0, 0);
    } else if (b < 66) {                            // psum 16384 + cnt 256 = 16640 f = 4160 float4
        const int idx = (b - 49) * 256 + t;
        if (idx < 4160) ((float4*)psum)[idx] = make_float4(0.f, 0.f, 0.f, 0.f);
    } else {
        for (int idx = t; idx < 2048; idx += 256) {
            const int n = idx >> 5, kp = idx & 31;
            W2p[idx] = pack2(W2[(2 * kp) * 64 + n], W2[(2 * kp + 1) * 64 + n]);
        }
    }
}

// ---------------------------------------------------------------- K1: partition (128-node buckets) + deg atomics + gemm1
// blocks [0,NC): partition; [NC,NC+NG1): gemm1 128-row tile.
__global__ __launch_bounds__(512) void part_gemm(const int* __restrict__ ei,
                                                 int* __restrict__ histg,
                                                 unsigned* __restrict__ ebuf,
                                                 int* __restrict__ deg,
                                                 const float* __restrict__ X,
                                                 const float* __restrict__ W,
                                                 unsigned short* __restrict__ Y) {
    __shared__ __align__(16) char smem[52224];
    const int t = threadIdx.x;

    if (blockIdx.x < NC) {
        // ---------------- partition path ----------------
        int* hist = (int*)smem;                       // 512
        int* incl = hist + 512;                       // 512
        int* lcur = incl + 512;                       // 512
        int* wq   = lcur + 512;                       // 8
        unsigned* lpairs = (unsigned*)(smem + 6176);  // 4096 entries
        const int c = blockIdx.x;
        const int c0 = c * CH;

        hist[t] = 0;
        __syncthreads();

        int es[8], ed[8];
#pragma unroll
        for (int j = 0; j < 2; ++j) {
            const int e = c0 + (j * 512 + t) * 4;
            int4 s4 = make_int4(-1, -1, -1, -1);
            int4 d4 = make_int4(-1, -1, -1, -1);
            if (e + 3 < NE) {
                s4 = *(const int4*)&ei[e];
                d4 = *(const int4*)&ei[NE + e];
            } else {
                if (e < NE)     { s4.x = ei[e];     d4.x = ei[NE + e]; }
                if (e + 1 < NE) { s4.y = ei[e + 1]; d4.y = ei[NE + e + 1]; }
                if (e + 2 < NE) { s4.z = ei[e + 2]; d4.z = ei[NE + e + 2]; }
            }
            es[4*j] = s4.x; es[4*j+1] = s4.y; es[4*j+2] = s4.z; es[4*j+3] = s4.w;
            ed[4*j] = d4.x; ed[4*j+1] = d4.y; ed[4*j+2] = d4.z; ed[4*j+3] = d4.w;
            if (d4.x >= 0) { atomicAdd(&hist[d4.x >> 7], 1); atomicAdd(&deg[d4.x], 1); }
            if (d4.y >= 0) { atomicAdd(&hist[d4.y >> 7], 1); atomicAdd(&deg[d4.y], 1); }
            if (d4.z >= 0) { atomicAdd(&hist[d4.z >> 7], 1); atomicAdd(&deg[d4.z], 1); }
            if (d4.w >= 0) { atomicAdd(&hist[d4.w >> 7], 1); atomicAdd(&deg[d4.w], 1); }
        }
        __syncthreads();

        // shfl inclusive scan over 512 bins
        const int v = hist[t];
        int sv = v;
#pragma unroll
        for (int off = 1; off < 64; off <<= 1) {
            int u = __shfl_up(sv, off, 64);
            if ((t & 63) >= off) sv += u;
        }
        if ((t & 63) == 63) wq[t >> 6] = sv;
        __syncthreads();
        {
            const int wid = t >> 6;
            int add = 0;
            for (int ww = 0; ww < wid; ++ww) add += wq[ww];
            sv += add;
        }
        incl[t] = sv;
        lcur[t] = sv - v;
        if (t < NBA) histg[c * NBA + t] = v;
        __syncthreads();

#pragma unroll
        for (int j = 0; j < 8; ++j) {
            const int d = ed[j];
            if (d >= 0) {
                int p = atomicAdd(&lcur[d >> 7], 1);
                lpairs[p] = (unsigned)es[j] | ((unsigned)d << 16);
            }
        }
        __syncthreads();

        const int total = incl[511];
        for (int p = t; p < total; p += 512) {
            const unsigned pr = lpairs[p];
            const int b = pr >> 23;                   // dst>>7
            const int i = p - (incl[b] - hist[b]);
            ebuf[(b * NC + c) * CELL + i] = pr;
        }
    } else {
        // ---------------- gemm1 path: 128 rows, 8 waves ----------------
        const int gb = blockIdx.x - NC;
        unsigned short* Xs = (unsigned short*)smem;       // 128*136 bf16 = 34816 B
        unsigned int* Wt = (unsigned int*)(smem + 34816); // 64*68 packed = 17408 B
        const int base = gb * 128;

        for (int i = t * 4; i < 128 * 128; i += 2048) {
            int node = i >> 7, k = i & 127;
            int gn = base + node; if (gn >= NN) gn = NN - 1;
            float4 v = *(const float4*)&X[(size_t)gn * 128 + k];
            ushort4 o = { f2bf(v.x), f2bf(v.y), f2bf(v.z), f2bf(v.w) };
            *(ushort4*)&Xs[node * 136 + k] = o;
        }
        for (int idx = t; idx < 64 * 64; idx += 512) {
            int n = idx & 63, kp = idx >> 6;
            float w0 = W[(2 * kp) * 64 + n];
            float w1 = W[(2 * kp + 1) * 64 + n];
            Wt[n * 68 + kp] = (unsigned)f2bf(w0) | ((unsigned)f2bf(w1) << 16);
        }
        __syncthreads();

        const int w = t >> 6;          // 8 waves
        const int sub = w >> 2;        // row half (0/1)
        const int wl = w & 3;          // 16-row tile within half
        const int lane = t & 63;
        const int l15 = lane & 15;
        const int quad = lane >> 4;
        f32x4 acc[4] = {{0.f,0.f,0.f,0.f},{0.f,0.f,0.f,0.f},{0.f,0.f,0.f,0.f},{0.f,0.f,0.f,0.f}};
#pragma unroll
        for (int kk = 0; kk < 4; ++kk) {
            const bf16x8 a = *(const bf16x8*)&Xs[(sub * 64 + wl * 16 + l15) * 136 + quad * 8 + kk * 32];
#pragma unroll
            for (int nt = 0; nt < 4; ++nt) {
                const bf16x8 b = *(const bf16x8*)&Wt[(nt * 16 + l15) * 68 + quad * 4 + kk * 16];
                acc[nt] = __builtin_amdgcn_mfma_f32_16x16x32_bf16(a, b, acc[nt], 0, 0, 0);
            }
        }
        const int r0 = base + sub * 64 + wl * 16 + quad * 4;
#pragma unroll
        for (int reg = 0; reg < 4; ++reg) {
            const int row = r0 + reg;
            if (row < NN) {
#pragma unroll
                for (int nt = 0; nt < 4; ++nt)
                    Y[(size_t)row * 64 + nt * 16 + l15] = f2bf(acc[nt][reg]);
            }
        }
    }
}

// ---------------------------------------------------------------- bucket edge staging (shared by agg kernels)
// Copies the bucket's cells (per-chunk counts in histg) into ledges[]; returns total via coffs[255].
static __device__ __forceinline__ int stage_edges(const unsigned* __restrict__ ebuf,
                                                  const int* __restrict__ histg,
                                                  int b, int t,
                                                  int* coffs, int* cvs, int* wq,
                                                  unsigned* ledges) {
    const int cv = (t < NC) ? histg[t * NBA + b] : 0;
    if (t < 256) {
        int sv = cv;
#pragma unroll
        for (int off = 1; off < 64; off <<= 1) {
            int u = __shfl_up(sv, off, 64);
            if ((t & 63) >= off) sv += u;
        }
        if ((t & 63) == 63) wq[t >> 6] = sv;
        cvs[t] = cv;
        coffs[t] = sv;     // partial; fixed after barrier
    }
    __syncthreads();
    if (t < 256) {
        const int wid = t >> 6;
        int add = 0;
        if (wid > 0) add += wq[0];
        if (wid > 1) add += wq[1];
        if (wid > 2) add += wq[2];
        coffs[t] += add;
    }
    __syncthreads();
    // 2 threads per cell, even/odd uint4 groups (CELL=40 -> 10 uint4)
    {
        const int tc = t & 255;
        const int cv2 = cvs[tc];
        if (tc < NC && cv2 > 0) {
            const uint4* src4 = (const uint4*)&ebuf[(size_t)(b * NC + tc) * CELL];
            const int dst = coffs[tc] - cv2;
            for (int g4 = (t >> 8); g4 * 4 < cv2; g4 += 2) {
                const uint4 u = src4[g4];
                const int i = g4 * 4;
                ledges[dst + i] = u.x;
                if (i + 1 < cv2) ledges[dst + i + 1] = u.y;
                if (i + 2 < cv2) ledges[dst + i + 2] = u.z;
                if (i + 3 < cv2) ledges[dst + i + 3] = u.w;
            }
        }
    }
    return coffs[255];
}

// ---------------------------------------------------------------- K2: layer-1 aggregation via LDS atomics (391 blocks, 512 thr)
__global__ __launch_bounds__(512) void agg1(const unsigned short* __restrict__ h,
                                            const int* __restrict__ histg,
                                            const unsigned* __restrict__ ebuf,
                                            const int* __restrict__ deg,
                                            const float* __restrict__ b1,
                                            unsigned short* __restrict__ bufH) {
    __shared__ int coffs[256], cvs[256], wq[8];
    __shared__ unsigned ledges[ECAP];
    __shared__ float accf[128 * 64];
    const int b = blockIdx.x, t = threadIdx.x;

    // init accumulator with self-loop contribution: dis[n]*h[n]
    const int nl = t >> 2, q = t & 3;
    const int n = b * 128 + nl;
    float dn = 0.f;
    if (n < NN) {
        dn = rsqrtf((float)(deg[n] + 1));
        const uint4 u0 = *(const uint4*)&h[(n << 6) + q * 16];
        const uint4 u1 = *(const uint4*)&h[(n << 6) + q * 16 + 8];
        float* a = &accf[nl * 64 + q * 16];
        a[0] = lo16(u0.x) * dn; a[1] = hi16(u0.x) * dn;
        a[2] = lo16(u0.y) * dn; a[3] = hi16(u0.y) * dn;
        a[4] = lo16(u0.z) * dn; a[5] = hi16(u0.z) * dn;
        a[6] = lo16(u0.w) * dn; a[7] = hi16(u0.w) * dn;
        a[8]  = lo16(u1.x) * dn; a[9]  = hi16(u1.x) * dn;
        a[10] = lo16(u1.y) * dn; a[11] = hi16(u1.y) * dn;
        a[12] = lo16(u1.z) * dn; a[13] = hi16(u1.z) * dn;
        a[14] = lo16(u1.w) * dn; a[15] = hi16(u1.w) * dn;
    }
    const int total = stage_edges(ebuf, histg, b, t, coffs, cvs, wq, ledges);
    __syncthreads();

    // stream edges: 8 lanes/edge, 64 edges in flight, 4-deep unroll
    const int g = t >> 3, k = t & 7;
    int i = g;
    for (; i + 192 < total; i += 256) {
        const unsigned e0 = ledges[i], e1 = ledges[i + 64], e2 = ledges[i + 128], e3 = ledges[i + 192];
        const int s0 = e0 & 0xFFFF, s1 = e1 & 0xFFFF, s2 = e2 & 0xFFFF, s3 = e3 & 0xFFFF;
        const int d0 = deg[s0], d1 = deg[s1], d2 = deg[s2], d3 = deg[s3];
        const uint4 u0 = *(const uint4*)&h[(s0 << 6) + k * 8];
        const uint4 u1 = *(const uint4*)&h[(s1 << 6) + k * 8];
        const uint4 u2 = *(const uint4*)&h[(s2 << 6) + k * 8];
        const uint4 u3 = *(const uint4*)&h[(s3 << 6) + k * 8];
        const float f0 = rsqrtf((float)(d0 + 1)), f1 = rsqrtf((float)(d1 + 1));
        const float f2 = rsqrtf((float)(d2 + 1)), f3 = rsqrtf((float)(d3 + 1));
        float* a0 = &accf[((e0 >> 16) & 127) * 64 + k * 8];
        float* a1 = &accf[((e1 >> 16) & 127) * 64 + k * 8];
        float* a2 = &accf[((e2 >> 16) & 127) * 64 + k * 8];
        float* a3 = &accf[((e3 >> 16) & 127) * 64 + k * 8];
        atomicAdd(a0+0, lo16(u0.x)*f0); atomicAdd(a0+1, hi16(u0.x)*f0);
        atomicAdd(a0+2, lo16(u0.y)*f0); atomicAdd(a0+3, hi16(u0.y)*f0);
        atomicAdd(a0+4, lo16(u0.z)*f0); atomicAdd(a0+5, hi16(u0.z)*f0);
        atomicAdd(a0+6, lo16(u0.w)*f0); atomicAdd(a0+7, hi16(u0.w)*f0);
        atomicAdd(a1+0, lo16(u1.x)*f1); atomicAdd(a1+1, hi16(u1.x)*f1);
        atomicAdd(a1+2, lo16(u1.y)*f1); atomicAdd(a1+3, hi16(u1.y)*f1);
        atomicAdd(a1+4, lo16(u1.z)*f1); atomicAdd(a1+5, hi16(u1.z)*f1);
        atomicAdd(a1+6, lo16(u1.w)*f1); atomicAdd(a1+7, hi16(u1.w)*f1);
        atomicAdd(a2+0, lo16(u2.x)*f2); atomicAdd(a2+1, hi16(u2.x)*f2);
        atomicAdd(a2+2, lo16(u2.y)*f2); atomicAdd(a2+3, hi16(u2.y)*f2);
        atomicAdd(a2+4, lo16(u2.z)*f2); atomicAdd(a2+5, hi16(u2.z)*f2);
        atomicAdd(a2+6, lo16(u2.w)*f2); atomicAdd(a2+7, hi16(u2.w)*f2);
        atomicAdd(a3+0, lo16(u3.x)*f3); atomicAdd(a3+1, hi16(u3.x)*f3);
        atomicAdd(a3+2, lo16(u3.y)*f3); atomicAdd(a3+3, hi16(u3.y)*f3);
        atomicAdd(a3+4, lo16(u3.z)*f3); atomicAdd(a3+5, hi16(u3.z)*f3);
        atomicAdd(a3+6, lo16(u3.w)*f3); atomicAdd(a3+7, hi16(u3.w)*f3);
    }
    for (; i < total; i += 64) {
        const unsigned e = ledges[i];
        const int s = e & 0xFFFF;
        const float f = rsqrtf((float)(deg[s] + 1));
        const uint4 u = *(const uint4*)&h[(s << 6) + k * 8];
        float* a = &accf[((e >> 16) & 127) * 64 + k * 8];
        atomicAdd(a+0, lo16(u.x)*f); atomicAdd(a+1, hi16(u.x)*f);
        atomicAdd(a+2, lo16(u.y)*f); atomicAdd(a+3, hi16(u.y)*f);
        atomicAdd(a+4, lo16(u.z)*f); atomicAdd(a+5, hi16(u.z)*f);
        atomicAdd(a+6, lo16(u.w)*f); atomicAdd(a+7, hi16(u.w)*f);
    }
    __syncthreads();

    // epilogue: h1 = relu(acc*dn + b1) -> bf16
    if (n < NN) {
        const float* a = &accf[nl * 64 + q * 16];
        const float4 bv0 = *(const float4*)&b1[q * 16];
        const float4 bv1 = *(const float4*)&b1[q * 16 + 4];
        const float4 bv2 = *(const float4*)&b1[q * 16 + 8];
        const float4 bv3 = *(const float4*)&b1[q * 16 + 12];
        uint4 p0, p1;
        p0.x = pack2(fmaxf(a[0]*dn + bv0.x, 0.f), fmaxf(a[1]*dn + bv0.y, 0.f));
        p0.y = pack2(fmaxf(a[2]*dn + bv0.z, 0.f), fmaxf(a[3]*dn + bv0.w, 0.f));
        p0.z = pack2(fmaxf(a[4]*dn + bv1.x, 0.f), fmaxf(a[5]*dn + bv1.y, 0.f));
        p0.w = pack2(fmaxf(a[6]*dn + bv1.z, 0.f), fmaxf(a[7]*dn + bv1.w, 0.f));
        p1.x = pack2(fmaxf(a[8]*dn  + bv2.x, 0.f), fmaxf(a[9]*dn  + bv2.y, 0.f));
        p1.y = pack2(fmaxf(a[10]*dn + bv2.z, 0.f), fmaxf(a[11]*dn + bv2.w, 0.f));
        p1.z = pack2(fmaxf(a[12]*dn + bv3.x, 0.f), fmaxf(a[13]*dn + bv3.y, 0.f));
        p1.w = pack2(fmaxf(a[14]*dn + bv3.z, 0.f), fmaxf(a[15]*dn + bv3.w, 0.f));
        *(uint4*)&bufH[(n << 6) + q * 16] = p0;
        *(uint4*)&bufH[(n << 6) + q * 16 + 8] = p1;
    }
}

// ---------------------------------------------------------------- K3: gemm2 = bufH @ W2, pre-scaled by dis[row]
__global__ __launch_bounds__(256) void gemm2(const unsigned short* __restrict__ bufH,
                                             const unsigned* __restrict__ W2p,
                                             const int* __restrict__ deg,
                                             unsigned short* __restrict__ bufB) {
    __shared__ unsigned short Ah[64 * 72];
    __shared__ unsigned short W2b[64 * 72];
    const int t = threadIdx.x;
    const int base = blockIdx.x * 64;
    for (int i = t * 8; i < 64 * 64; i += 2048) {
        const int node = i >> 6, k = i & 63;
        *(uint4*)&Ah[node * 72 + k] = *(const uint4*)&bufH[(size_t)(base + node) * 64 + k];
    }
    for (int idx = t; idx < 2048; idx += 256) {
        const int nn2 = idx >> 5, kp = idx & 31;
        *(unsigned*)&W2b[nn2 * 72 + 2 * kp] = W2p[idx];
    }
    __syncthreads();

    const int w = t >> 6;
    const int lane = t & 63;
    const int l15 = lane & 15;
    const int quad = lane >> 4;
    f32x4 acc[4] = {{0.f,0.f,0.f,0.f},{0.f,0.f,0.f,0.f},{0.f,0.f,0.f,0.f},{0.f,0.f,0.f,0.f}};
#pragma unroll
    for (int kk = 0; kk < 2; ++kk) {
        const bf16x8 a = *(const bf16x8*)&Ah[(w * 16 + l15) * 72 + quad * 8 + kk * 32];
#pragma unroll
        for (int nt = 0; nt < 4; ++nt) {
            const bf16x8 b = *(const bf16x8*)&W2b[(nt * 16 + l15) * 72 + quad * 8 + kk * 32];
            acc[nt] = __builtin_amdgcn_mfma_f32_16x16x32_bf16(a, b, acc[nt], 0, 0, 0);
        }
    }
    const int r0 = base + w * 16 + quad * 4;
    const int4 dg = *(const int4*)&deg[r0];     // tail over-read; stores guarded
    const float dd[4] = { rsqrtf((float)(dg.x + 1)), rsqrtf((float)(dg.y + 1)),
                          rsqrtf((float)(dg.z + 1)), rsqrtf((float)(dg.w + 1)) };
#pragma unroll
    for (int reg = 0; reg < 4; ++reg) {
        const int row = r0 + reg;
        if (row < NN) {
#pragma unroll
            for (int nt = 0; nt < 4; ++nt)
                bufB[(size_t)row * 64 + nt * 16 + l15] = f2bf(acc[nt][reg] * dd[reg]);
        }
    }
}

// ---------------------------------------------------------------- K4: layer-2 aggregation + pooling (391 blocks, 512 thr)
__global__ __launch_bounds__(512) void agg2_pool(const unsigned short* __restrict__ h,
                                                 const int* __restrict__ histg,
                                                 const unsigned* __restrict__ ebuf,
                                                 const int* __restrict__ deg,
                                                 const float* __restrict__ b2,
                                                 const int* __restrict__ batch,
                                                 float* __restrict__ psum,
                                                 float* __restrict__ cnt) {
    __shared__ int coffs[256], cvs[256], wq[8];
    __shared__ unsigned ledges[ECAP];
    __shared__ float accf[128 * 64];
    __shared__ int nb[128];
    const int b = blockIdx.x, t = threadIdx.x;

    // init accumulator with self-loop contribution: bufB row is pre-scaled by dis[n]
    const int nl = t >> 2, q = t & 3;
    const int n = b * 128 + nl;
    float dn = 0.f;
    if (n < NN) {
        dn = rsqrtf((float)(deg[n] + 1));
        const uint4 u0 = *(const uint4*)&h[(n << 6) + q * 16];
        const uint4 u1 = *(const uint4*)&h[(n << 6) + q * 16 + 8];
        float* a = &accf[nl * 64 + q * 16];
        a[0] = lo16(u0.x); a[1] = hi16(u0.x);
        a[2] = lo16(u0.y); a[3] = hi16(u0.y);
        a[4] = lo16(u0.z); a[5] = hi16(u0.z);
        a[6] = lo16(u0.w); a[7] = hi16(u0.w);
        a[8]  = lo16(u1.x); a[9]  = hi16(u1.x);
        a[10] = lo16(u1.y); a[11] = hi16(u1.y);
        a[12] = lo16(u1.z); a[13] = hi16(u1.z);
        a[14] = lo16(u1.w); a[15] = hi16(u1.w);
    }
    if (t < 128) {
        const int nn2 = b * 128 + t;
        nb[t] = (nn2 < NN) ? batch[nn2] : -1;
    }
    const int total = stage_edges(ebuf, histg, b, t, coffs, cvs, wq, ledges);
    __syncthreads();

    // stream edges (rows pre-scaled: plain adds)
    const int g = t >> 3, k = t & 7;
    int i = g;
    for (; i + 192 < total; i += 256) {
        const unsigned e0 = ledges[i], e1 = ledges[i + 64], e2 = ledges[i + 128], e3 = ledges[i + 192];
        const int s0 = e0 & 0xFFFF, s1 = e1 & 0xFFFF, s2 = e2 & 0xFFFF, s3 = e3 & 0xFFFF;
        const uint4 u0 = *(const uint4*)&h[(s0 << 6) + k * 8];
        const uint4 u1 = *(const uint4*)&h[(s1 << 6) + k * 8];
        const uint4 u2 = *(const uint4*)&h[(s2 << 6) + k * 8];
        const uint4 u3 = *(const uint4*)&h[(s3 << 6) + k * 8];
        float* a0 = &accf[((e0 >> 16) & 127) * 64 + k * 8];
        float* a1 = &accf[((e1 >> 16) & 127) * 64 + k * 8];
        float* a2 = &accf[((e2 >> 16) & 127) * 64 + k * 8];
        float* a3 = &accf[((e3 >> 16) & 127) * 64 + k * 8];
        atomicAdd(a0+0, lo16(u0.x)); atomicAdd(a0+1, hi16(u0.x));
        atomicAdd(a0+2, lo16(u0.y)); atomicAdd(a0+3, hi16(u0.y));
        atomicAdd(a0+4, lo16(u0.z)); atomicAdd(a0+5, hi16(u0.z));
        atomicAdd(a0+6, lo16(u0.w)); atomicAdd(a0+7, hi16(u0.w));
        atomicAdd(a1+0, lo16(u1.x)); atomicAdd(a1+1, hi16(u1.x));
        atomicAdd(a1+2, lo16(u1.y)); atomicAdd(a1+3, hi16(u1.y));
        atomicAdd(a1+4, lo16(u1.z)); atomicAdd(a1+5, hi16(u1.z));
        atomicAdd(a1+6, lo16(u1.w)); atomicAdd(a1+7, hi16(u1.w));
        atomicAdd(a2+0, lo16(u2.x)); atomicAdd(a2+1, hi16(u2.x));
        atomicAdd(a2+2, lo16(u2.y)); atomicAdd(a2+3, hi16(u2.y));
        atomicAdd(a2+4, lo16(u2.z)); atomicAdd(a2+5, hi16(u2.z));
        atomicAdd(a2+6, lo16(u2.w)); atomicAdd(a2+7, hi16(u2.w));
        atomicAdd(a3+0, lo16(u3.x)); atomicAdd(a3+1, hi16(u3.x));
        atomicAdd(a3+2, lo16(u3.y)); atomicAdd(a3+3, hi16(u3.y));
        atomicAdd(a3+4, lo16(u3.z)); atomicAdd(a3+5, hi16(u3.z));
        atomicAdd(a3+6, lo16(u3.w)); atomicAdd(a3+7, hi16(u3.w));
    }
    for (; i < total; i += 64) {
        const unsigned e = ledges[i];
        const int s = e & 0xFFFF;
        const uint4 u = *(const uint4*)&h[(s << 6) + k * 8];
        float* a = &accf[((e >> 16) & 127) * 64 + k * 8];
        atomicAdd(a+0, lo16(u.x)); atomicAdd(a+1, hi16(u.x));
        atomicAdd(a+2, lo16(u.y)); atomicAdd(a+3, hi16(u.y));
        atomicAdd(a+4, lo16(u.z)); atomicAdd(a+5, hi16(u.z));
        atomicAdd(a+6, lo16(u.w)); atomicAdd(a+7, hi16(u.w));
    }
    __syncthreads();

    // transform rows in place: h2 = relu(acc*dn + b2)
    if (n < NN) {
        float* a = &accf[nl * 64 + q * 16];
        const float4 bv0 = *(const float4*)&b2[q * 16];
        const float4 bv1 = *(const float4*)&b2[q * 16 + 4];
        const float4 bv2 = *(const float4*)&b2[q * 16 + 8];
        const float4 bv3 = *(const float4*)&b2[q * 16 + 12];
        a[0] = fmaxf(a[0]*dn + bv0.x, 0.f);  a[1] = fmaxf(a[1]*dn + bv0.y, 0.f);
        a[2] = fmaxf(a[2]*dn + bv0.z, 0.f);  a[3] = fmaxf(a[3]*dn + bv0.w, 0.f);
        a[4] = fmaxf(a[4]*dn + bv1.x, 0.f);  a[5] = fmaxf(a[5]*dn + bv1.y, 0.f);
        a[6] = fmaxf(a[6]*dn + bv1.z, 0.f);  a[7] = fmaxf(a[7]*dn + bv1.w, 0.f);
        a[8]  = fmaxf(a[8]*dn  + bv2.x, 0.f); a[9]  = fmaxf(a[9]*dn  + bv2.y, 0.f);
        a[10] = fmaxf(a[10]*dn + bv2.z, 0.f); a[11] = fmaxf(a[11]*dn + bv2.w, 0.f);
        a[12] = fmaxf(a[12]*dn + bv3.x, 0.f); a[13] = fmaxf(a[13]*dn + bv3.y, 0.f);
        a[14] = fmaxf(a[14]*dn + bv3.z, 0.f); a[15] = fmaxf(a[15]*dn + bv3.w, 0.f);
    }
    __syncthreads();

    // pooling: run-length over 128 sorted rows, one 64-lane wave
    if (t < 64) {
        float s = 0.f; int curg = -2; int rl = 0;
        for (int r = 0; r < 128; ++r) {
            const int gg = nb[r];                 // wave-uniform
            if (gg != curg) {
                if (curg >= 0) {
                    atomicAdd(&psum[curg * 64 + t], s);
                    if (t == 0) atomicAdd(&cnt[curg], (float)rl);
                }
                s = 0.f; rl = 0; curg = gg;
            }
            if (gg >= 0) { s += accf[r * 64 + t]; ++rl; }
        }
        if (curg >= 0) {
            atomicAdd(&psum[curg * 64 + t], s);
            if (t == 0) atomicAdd(&cnt[curg], (float)rl);
        }
    }
}

// ---------------------------------------------------------------- K5: head — mean + MLP
__global__ __launch_bounds__(64) void head_kernel(const float* __restrict__ psum,
                                                  const float* __restrict__ cnt,
                                                  const float* __restrict__ Wm1,
                                                  const float* __restrict__ bm1,
                                                  const float* __restrict__ Wm2,
                                                  const float* __restrict__ bm2,
                                                  float* __restrict__ out) {
    const int g = blockIdx.x;
    const int t = threadIdx.x;
    __shared__ float pl[64];
    const float inv = 1.f / fmaxf(cnt[g], 1.f);
    pl[t] = psum[g * 64 + t] * inv;
    __syncthreads();
    float z = bm1[t];
#pragma unroll 8
    for (int k = 0; k < 64; ++k)
        z += pl[k] * Wm1[k * 64 + t];
    z = fmaxf(z, 0.f);
    float y = z * Wm2[t];
    for (int off = 32; off; off >>= 1) y += __shfl_down(y, off);
    if (t == 0) out[g] = y + bm2[0];
}

// ---------------------------------------------------------------- launch
extern "C" void kernel_launch(void* const* d_in, const int* in_sizes, int n_in,
                              void* d_out, int out_size, void* d_ws, size_t ws_size,
                              hipStream_t stream) {
    const float* x   = (const float*)d_in[0];
    const int*   ei  = (const int*)d_in[1];
    const int*   bat = (const int*)d_in[2];
    const float* W1  = (const float*)d_in[3];
    const float* b1  = (const float*)d_in[4];
    const float* W2  = (const float*)d_in[5];
    const float* b2  = (const float*)d_in[6];
    const float* Wm1 = (const float*)d_in[7];
    const float* bm1 = (const float*)d_in[8];
    const float* Wm2 = (const float*)d_in[9];
    const float* bm2 = (const float*)d_in[10];
    float* out = (float*)d_out;

    char* w = (char*)d_ws;
    int*            deg   = (int*)           (w + 0);          //   200704 B (50176 ints)
    int*            histg = (int*)           (w + 200704);     //   307328 B (196 x 392)
    unsigned*       ebuf  = (unsigned*)      (w + 508032);     // 12293120 B (392*196*40 packed edges)
    unsigned short* bufA  = (unsigned short*)(w + 12801152);   //  6422528 B (50176 x 64 bf16)
    unsigned short* bufH  = (unsigned short*)(w + 19223680);   //  6422528 B
    unsigned short* bufB  = (unsigned short*)(w + 25646208);   //  6422528 B
    float*          psum  = (float*)         (w + 32068736);   //    66560 B (16384 psum + 256 cnt)
    unsigned*       W2p   = (unsigned*)      (w + 32135296);   //     8192 B
    float*          cnt   = psum + 16384;

    zero_init  <<<67, 256, 0, stream>>>(deg, psum, W2, W2p);
    part_gemm  <<<NC + NG1, 512, 0, stream>>>(ei, histg, ebuf, deg, x, W1, bufA);
    agg1       <<<NBK, 512, 0, stream>>>(bufA, histg, ebuf, deg, b1, bufH);
    gemm2      <<<NG2, 256, 0, stream>>>(bufH, W2p, deg, bufB);
    agg2_pool  <<<NBK, 512, 0, stream>>>(bufB, histg, ebuf, deg, b2, bat, psum, cnt);
    head_kernel<<<NG, 64, 0, stream>>>(psum, cnt, Wm1, bm1, Wm2, bm2, out);
}

// Round 10
// 150.704 us; speedup vs baseline: 5.6853x; 5.6853x over previous
//
#include <hip/hip_runtime.h>

#define NN 50000            // nodes
#define NE 800000           // edges
#define NF 128              // input features
#define NH 64               // hidden
#define NG 256              // graphs
#define NB 196              // buckets of 256 dst nodes
#define NC 196              // chunks: ceil(NE/CH)
#define CH 4096             // edges per partition block
#define CELL 80             // per-(chunk,bucket) capacity (packed 4B entries)
#define CAP 5120            // per-bucket CSR capacity
#define NGB 782             // gemm blocks: ceil(NN/64)

typedef __attribute__((ext_vector_type(8))) short bf16x8;
typedef __attribute__((ext_vector_type(4))) float f32x4;

static __device__ __forceinline__ unsigned short f2bf(float f) {
    union { float f; unsigned u; } v; v.f = f;
    unsigned r = v.u + 0x7FFF + ((v.u >> 16) & 1);   // RNE
    return (unsigned short)(r >> 16);
}
static __device__ __forceinline__ float lo16(unsigned u) {
    return __uint_as_float(u << 16);
}
static __device__ __forceinline__ float hi16(unsigned u) {
    return __uint_as_float(u & 0xFFFF0000u);
}
static __device__ __forceinline__ unsigned pack2(float a, float b) {
    return (unsigned)f2bf(a) | ((unsigned)f2bf(b) << 16);
}

// ---------------------------------------------------------------- fused: psum-zero + partition + gemm1 + W2 pack
__global__ __launch_bounds__(256) void prep_gemm(const int* __restrict__ ei,
                                                 int* __restrict__ histg,
                                                 unsigned* __restrict__ ebuf,
                                                 const float* __restrict__ X,
                                                 const float* __restrict__ W,
                                                 const float* __restrict__ W2,
                                                 unsigned short* __restrict__ Y,
                                                 float* __restrict__ psum,
                                                 unsigned* __restrict__ W2p) {
    __shared__ __align__(16) char smem[35840];
    const int t = threadIdx.x;

    if (blockIdx.x < NC) {
        // ---------------- partition path ----------------
        int* hist = (int*)smem;                    // 256
        int* incl = hist + 256;                    // 256
        int* lcur = incl + 256;                    // 256
        int* wq   = lcur + 256;                    // 4
        unsigned* lpairs = (unsigned*)(smem + 4096); // 4096 entries
        const int c = blockIdx.x;
        const int c0 = c * CH;

        hist[t] = 0;
        __syncthreads();

        int es[16], ed[16];
#pragma unroll
        for (int j = 0; j < 4; ++j) {
            const int e = c0 + (j * 256 + t) * 4;
            int4 s4 = make_int4(-1, -1, -1, -1);
            int4 d4 = make_int4(-1, -1, -1, -1);
            if (e + 3 < NE) {
                s4 = *(const int4*)&ei[e];
                d4 = *(const int4*)&ei[NE + e];
            } else {
                if (e < NE)     { s4.x = ei[e];     d4.x = ei[NE + e]; }
                if (e + 1 < NE) { s4.y = ei[e + 1]; d4.y = ei[NE + e + 1]; }
                if (e + 2 < NE) { s4.z = ei[e + 2]; d4.z = ei[NE + e + 2]; }
            }
            es[4*j] = s4.x; es[4*j+1] = s4.y; es[4*j+2] = s4.z; es[4*j+3] = s4.w;
            ed[4*j] = d4.x; ed[4*j+1] = d4.y; ed[4*j+2] = d4.z; ed[4*j+3] = d4.w;
            if (d4.x >= 0) atomicAdd(&hist[d4.x >> 8], 1);
            if (d4.y >= 0) atomicAdd(&hist[d4.y >> 8], 1);
            if (d4.z >= 0) atomicAdd(&hist[d4.z >> 8], 1);
            if (d4.w >= 0) atomicAdd(&hist[d4.w >> 8], 1);
        }
        __syncthreads();

        // shfl-based inclusive scan of hist[256] (2 barriers)
        const int v = hist[t];
        int sv = v;
#pragma unroll
        for (int off = 1; off < 64; off <<= 1) {
            int u = __shfl_up(sv, off, 64);
            if ((t & 63) >= off) sv += u;
        }
        if ((t & 63) == 63) wq[t >> 6] = sv;
        __syncthreads();
        {
            const int wid = t >> 6;
            int add = 0;
            if (wid > 0) add += wq[0];
            if (wid > 1) add += wq[1];
            if (wid > 2) add += wq[2];
            sv += add;
        }
        incl[t] = sv;
        lcur[t] = sv - v;
        if (t < NB) histg[c * NB + t] = v;
        __syncthreads();

#pragma unroll
        for (int j = 0; j < 16; ++j) {
            const int d = ed[j];
            if (d >= 0) {
                int p = atomicAdd(&lcur[d >> 8], 1);
                lpairs[p] = (unsigned)es[j] | ((unsigned)d << 16);
            }
        }
        __syncthreads();

        const int total = incl[255];
        for (int p = t; p < total; p += 256) {
            const unsigned pr = lpairs[p];
            const int b = pr >> 24;                       // dst>>8
            const int i = p - (incl[b] - hist[b]);
            ebuf[(b * NC + c) * CELL + i] = pr;
        }
    } else {
        const int gb = blockIdx.x - NC;
        if (gb >= NGB) {
            // ---------------- W2 pack path (single block) ----------------
            for (int idx = t; idx < 2048; idx += 256) {
                const int n = idx >> 5, kp = idx & 31;
                W2p[idx] = pack2(W2[(2 * kp) * 64 + n], W2[(2 * kp + 1) * 64 + n]);
            }
            return;
        }
        // ---------------- gemm1 path ----------------
        if (gb < 17) {   // zero psum (16384) + cnt (256)
            const int o = gb * 1024 + t * 4;
            if (o < 16640) *(float4*)&psum[o] = make_float4(0.f, 0.f, 0.f, 0.f);
        }

        unsigned short* Xs = (unsigned short*)smem;       // 64*136 bf16
        unsigned int* Wt = (unsigned int*)(smem + 17408); // 64*68 packed
        const int base = gb * 64;

        for (int i = t * 4; i < 64 * 128; i += 1024) {
            int node = i >> 7, k = i & 127;
            int gn = base + node; if (gn >= NN) gn = NN - 1;
            float4 v = *(const float4*)&X[(size_t)gn * 128 + k];
            ushort4 o = { f2bf(v.x), f2bf(v.y), f2bf(v.z), f2bf(v.w) };
            *(ushort4*)&Xs[node * 136 + k] = o;
        }
        for (int idx = t; idx < 64 * 64; idx += 256) {
            int n = idx & 63, kp = idx >> 6;
            float w0 = W[(2 * kp) * 64 + n];
            float w1 = W[(2 * kp + 1) * 64 + n];
            Wt[n * 68 + kp] = (unsigned)f2bf(w0) | ((unsigned)f2bf(w1) << 16);
        }
        __syncthreads();

        const int w = t >> 6;
        const int lane = t & 63;
        const int l15 = lane & 15;
        const int quad = lane >> 4;
        f32x4 acc[4] = {{0.f,0.f,0.f,0.f},{0.f,0.f,0.f,0.f},{0.f,0.f,0.f,0.f},{0.f,0.f,0.f,0.f}};
#pragma unroll
        for (int kk = 0; kk < 4; ++kk) {
            const bf16x8 a = *(const bf16x8*)&Xs[(w * 16 + l15) * 136 + quad * 8 + kk * 32];
#pragma unroll
            for (int nt = 0; nt < 4; ++nt) {
                const bf16x8 b = *(const bf16x8*)&Wt[(nt * 16 + l15) * 68 + quad * 4 + kk * 16];
                acc[nt] = __builtin_amdgcn_mfma_f32_16x16x32_bf16(a, b, acc[nt], 0, 0, 0);
            }
        }
        const int r0 = base + w * 16 + quad * 4;
#pragma unroll
        for (int reg = 0; reg < 4; ++reg) {
            const int row = r0 + reg;
            if (row < NN) {
#pragma unroll
                for (int nt = 0; nt < 4; ++nt)
                    Y[(size_t)row * 64 + nt * 16 + l15] = f2bf(acc[nt][reg]);
            }
        }
    }
}

// ---------------------------------------------------------------- level-2: per-bucket CSR + dis
__global__ __launch_bounds__(512) void build_csr(const unsigned* __restrict__ ebuf,
                                                 const int* __restrict__ histg,
                                                 int2* __restrict__ row_range,
                                                 float* __restrict__ dis,
                                                 int* __restrict__ csr_src) {
    const int b = blockIdx.x, t = threadIdx.x;
    const int e0 = b * CAP;
    __shared__ int coffs[256];
    __shared__ int cvs[256];
    __shared__ int deg_l[256];
    __shared__ int pre[256];
    __shared__ int cur[256];
    __shared__ int wq[8];
    __shared__ unsigned lpairs[CAP];
    __shared__ int lsrc[CAP];

    int cv = 0;
    if (t < NC) cv = histg[t * NB + b];
    int sv = cv;
    if (t < 256) {
#pragma unroll
        for (int off = 1; off < 64; off <<= 1) {
            int u = __shfl_up(sv, off, 64);
            if ((t & 63) >= off) sv += u;
        }
        if ((t & 63) == 63) wq[t >> 6] = sv;
        deg_l[t] = (b * 256 + t < NN) ? 1 : 0;   // self-loop
        cvs[t] = cv;
    }
    __syncthreads();
    if (t < 256) {
        const int wid = t >> 6;
        int add = 0;
        if (wid > 0) add += wq[0];
        if (wid > 1) add += wq[1];
        if (wid > 2) add += wq[2];
        coffs[t] = sv + add;
    }
    __syncthreads();

    // copy cells -> lpairs, 2 threads per cell (even/odd uint4 groups)
    {
        const int tc = t & 255;
        const int cv2 = cvs[tc];
        if (tc < NC && cv2 > 0) {
            const uint4* src4 = (const uint4*)&ebuf[(size_t)(b * NC + tc) * CELL];
            const int dst = coffs[tc] - cv2;
            for (int g4 = (t >> 8); g4 * 4 < cv2; g4 += 2) {
                const uint4 u = src4[g4];
                const int i = g4 * 4;
                lpairs[dst + i] = u.x;
                if (i + 1 < cv2) lpairs[dst + i + 1] = u.y;
                if (i + 2 < cv2) lpairs[dst + i + 2] = u.z;
                if (i + 3 < cv2) lpairs[dst + i + 3] = u.w;
            }
        }
    }
    __syncthreads();

    const int total = coffs[255];
    for (int i = t; i < total; i += 512)
        atomicAdd(&deg_l[(lpairs[i] >> 16) & 255], 1);
    __syncthreads();

    int dvi = 0, psv = 0;
    if (t < 256) {
        dvi = deg_l[t];
        psv = dvi;
#pragma unroll
        for (int off = 1; off < 64; off <<= 1) {
            int u = __shfl_up(psv, off, 64);
            if ((t & 63) >= off) psv += u;
        }
        if ((t & 63) == 63) wq[4 + (t >> 6)] = psv;
    }
    __syncthreads();
    if (t < 256) {
        const int wid = t >> 6;
        int add = 0;
        if (wid > 0) add += wq[4];
        if (wid > 1) add += wq[5];
        if (wid > 2) add += wq[6];
        psv += add;
        pre[t] = psv;
        cur[t] = 1;                        // slot 0 = self-loop
        const int nd = b * 256 + t;
        if (nd < NN) {
            const int excl = psv - dvi;
            lsrc[excl] = nd;
            row_range[nd] = make_int2(e0 + excl, e0 + psv);
            dis[nd] = rsqrtf((float)dvi);  // dvi = deg+1
        }
    }
    __syncthreads();

    for (int i = t; i < total; i += 512) {
        const unsigned p = lpairs[i];
        const int d = (p >> 16) & 255;
        const int pos = (pre[d] - deg_l[d]) + atomicAdd(&cur[d], 1);
        lsrc[pos] = (int)(p & 0xFFFFu);
    }
    __syncthreads();
    const int tot_all = pre[255];
    for (int i = t; i < tot_all; i += 512)
        csr_src[e0 + i] = lsrc[i];
}

// ---------------------------------------------------------------- gather cores (8 lanes/node, uint4, 8-deep batches,
//                                                                   shfl-distributed indices: 1 VMEM idx load per lane)
static __device__ __forceinline__ void acc8(float* acc, const uint4 u) {
    acc[0] += lo16(u.x); acc[1] += hi16(u.x);
    acc[2] += lo16(u.y); acc[3] += hi16(u.y);
    acc[4] += lo16(u.z); acc[5] += hi16(u.z);
    acc[6] += lo16(u.w); acc[7] += hi16(u.w);
}
static __device__ __forceinline__ void fma8(float* acc, const uint4 u, const float d) {
    acc[0] = fmaf(lo16(u.x), d, acc[0]); acc[1] = fmaf(hi16(u.x), d, acc[1]);
    acc[2] = fmaf(lo16(u.y), d, acc[2]); acc[3] = fmaf(hi16(u.y), d, acc[3]);
    acc[4] = fmaf(lo16(u.z), d, acc[4]); acc[5] = fmaf(hi16(u.z), d, acc[5]);
    acc[6] = fmaf(lo16(u.w), d, acc[6]); acc[7] = fmaf(hi16(u.w), d, acc[7]);
}

// pre-scaled rows (layer 2): 8-deep dependent batches
static __device__ __forceinline__ void gather_rows(const unsigned short* __restrict__ h,
                                                   const int* __restrict__ csr,
                                                   int lo, int hi, int p8, float* acc) {
    const int l7 = threadIdx.x & 7;            // lane within 8-lane node-group
    const int gb8 = (threadIdx.x & 63) & 56;   // group base lane within wave
    int i = lo;
    for (; i + 8 <= hi; i += 8) {
        const int myidx = csr[i + l7];         // ONE idx load per lane
        int idx[8];
#pragma unroll
        for (int j = 0; j < 8; ++j) idx[j] = __shfl(myidx, gb8 + j, 64);
        uint4 u[8];
#pragma unroll
        for (int j = 0; j < 8; ++j) u[j] = *(const uint4*)&h[(idx[j] << 6) + p8];
#pragma unroll
        for (int j = 0; j < 8; ++j) acc8(acc, u[j]);
    }
    if (i + 4 <= hi) {
        int idx[4];
#pragma unroll
        for (int j = 0; j < 4; ++j) idx[j] = csr[i + j];
        uint4 u[4];
#pragma unroll
        for (int j = 0; j < 4; ++j) u[j] = *(const uint4*)&h[(idx[j] << 6) + p8];
#pragma unroll
        for (int j = 0; j < 4; ++j) acc8(acc, u[j]);
        i += 4;
    }
    if (i + 2 <= hi) {
        const int i0 = csr[i], i1 = csr[i + 1];
        const uint4 u0 = *(const uint4*)&h[(i0 << 6) + p8];
        const uint4 u1 = *(const uint4*)&h[(i1 << 6) + p8];
        acc8(acc, u0); acc8(acc, u1);
        i += 2;
    }
    if (i < hi) acc8(acc, *(const uint4*)&h[(csr[i] << 6) + p8]);
}

// unscaled rows (layer 1): fold dis[src] at accumulate time, 8-deep batches
static __device__ __forceinline__ void gather_rows_scaled(const unsigned short* __restrict__ h,
                                                          const int* __restrict__ csr,
                                                          const float* __restrict__ dis,
                                                          int lo, int hi, int p8, float* acc) {
    const int l7 = threadIdx.x & 7;
    const int gb8 = (threadIdx.x & 63) & 56;
    int i = lo;
    for (; i + 8 <= hi; i += 8) {
        const int myidx = csr[i + l7];         // ONE idx load per lane
        const float myd = dis[myidx];          // ONE dis load per lane
        int idx[8];
#pragma unroll
        for (int j = 0; j < 8; ++j) idx[j] = __shfl(myidx, gb8 + j, 64);
        float d[8];
#pragma unroll
        for (int j = 0; j < 8; ++j) d[j] = __shfl(myd, gb8 + j, 64);
        uint4 u[8];
#pragma unroll
        for (int j = 0; j < 8; ++j) u[j] = *(const uint4*)&h[(idx[j] << 6) + p8];
#pragma unroll
        for (int j = 0; j < 8; ++j) fma8(acc, u[j], d[j]);
    }
    if (i + 4 <= hi) {
        int idx[4];
#pragma unroll
        for (int j = 0; j < 4; ++j) idx[j] = csr[i + j];
        float d[4];
#pragma unroll
        for (int j = 0; j < 4; ++j) d[j] = dis[idx[j]];
        uint4 u[4];
#pragma unroll
        for (int j = 0; j < 4; ++j) u[j] = *(const uint4*)&h[(idx[j] << 6) + p8];
#pragma unroll
        for (int j = 0; j < 4; ++j) fma8(acc, u[j], d[j]);
        i += 4;
    }
    if (i + 2 <= hi) {
        const int i0 = csr[i], i1 = csr[i + 1];
        const float d0 = dis[i0], d1 = dis[i1];
        const uint4 u0 = *(const uint4*)&h[(i0 << 6) + p8];
        const uint4 u1 = *(const uint4*)&h[(i1 << 6) + p8];
        fma8(acc, u0, d0); fma8(acc, u1, d1);
        i += 2;
    }
    if (i < hi) {
        const int i0 = csr[i];
        fma8(acc, *(const uint4*)&h[(i0 << 6) + p8], dis[i0]);
    }
}

// ---------------------------------------------------------------- agg1 + gemm2 fused (256 thr, 8 lanes/node)
__global__ __launch_bounds__(256) void agg_gemv(const unsigned short* __restrict__ h,
                                                const int2* __restrict__ row_range,
                                                const int* __restrict__ csr_src,
                                                const float* __restrict__ dis,
                                                const float* __restrict__ b1,
                                                const unsigned* __restrict__ W2p,
                                                unsigned short* __restrict__ g) {
    __shared__ unsigned short W2b[64 * 72];  // [n][k] bf16
    __shared__ unsigned short A[32 * 72];    // [m=node][k=dim] bf16
    const int t = threadIdx.x;
    const int base = blockIdx.x * 32;
    const int nloc = t >> 3;
    const int p8 = (t & 7) * 8;
    const int n = base + nloc;
    float acc[8] = {};
    if (n < NN) {
        const int2 rr = row_range[n];
        gather_rows_scaled(h, csr_src, dis, rr.x, rr.y, p8, acc);
        const float dn = dis[n];
        const float4 bv0 = *(const float4*)&b1[p8];
        const float4 bv1 = *(const float4*)&b1[p8 + 4];
        acc[0] = fmaxf(acc[0] * dn + bv0.x, 0.f);
        acc[1] = fmaxf(acc[1] * dn + bv0.y, 0.f);
        acc[2] = fmaxf(acc[2] * dn + bv0.z, 0.f);
        acc[3] = fmaxf(acc[3] * dn + bv0.w, 0.f);
        acc[4] = fmaxf(acc[4] * dn + bv1.x, 0.f);
        acc[5] = fmaxf(acc[5] * dn + bv1.y, 0.f);
        acc[6] = fmaxf(acc[6] * dn + bv1.z, 0.f);
        acc[7] = fmaxf(acc[7] * dn + bv1.w, 0.f);
    }
    for (int idx = t; idx < 2048; idx += 256) {   // stage W2 after gather (loads are independent)
        const int nn2 = idx >> 5, kp = idx & 31;
        *(unsigned*)&W2b[nn2 * 72 + 2 * kp] = W2p[idx];
    }
    uint4 pk;
    pk.x = pack2(acc[0], acc[1]);
    pk.y = pack2(acc[2], acc[3]);
    pk.z = pack2(acc[4], acc[5]);
    pk.w = pack2(acc[6], acc[7]);
    *(uint4*)&A[nloc * 72 + p8] = pk;
    __syncthreads();

    const int w = t >> 6;
    const int lane = t & 63;
    const int l15 = lane & 15;
    const int quad = lane >> 4;
    const int mt = w & 1;
    const int nq = (w >> 1) * 2;
    const bf16x8 a0 = *(const bf16x8*)&A[(mt * 16 + l15) * 72 + quad * 8];
    const bf16x8 a1 = *(const bf16x8*)&A[(mt * 16 + l15) * 72 + 32 + quad * 8];
    const bf16x8 b00 = *(const bf16x8*)&W2b[(nq * 16 + l15) * 72 + quad * 8];
    const bf16x8 b01 = *(const bf16x8*)&W2b[(nq * 16 + l15) * 72 + 32 + quad * 8];
    const bf16x8 b10 = *(const bf16x8*)&W2b[((nq + 1) * 16 + l15) * 72 + quad * 8];
    const bf16x8 b11 = *(const bf16x8*)&W2b[((nq + 1) * 16 + l15) * 72 + 32 + quad * 8];
    f32x4 c0 = {0.f, 0.f, 0.f, 0.f}, c1 = {0.f, 0.f, 0.f, 0.f};
    c0 = __builtin_amdgcn_mfma_f32_16x16x32_bf16(a0, b00, c0, 0, 0, 0);
    c0 = __builtin_amdgcn_mfma_f32_16x16x32_bf16(a1, b01, c0, 0, 0, 0);
    c1 = __builtin_amdgcn_mfma_f32_16x16x32_bf16(a0, b10, c1, 0, 0, 0);
    c1 = __builtin_amdgcn_mfma_f32_16x16x32_bf16(a1, b11, c1, 0, 0, 0);
    const int r0 = base + mt * 16 + quad * 4;
    float4 d4 = *(const float4*)&dis[r0];   // tail over-read; stores guarded
    const float dd[4] = { d4.x, d4.y, d4.z, d4.w };
#pragma unroll
    for (int reg = 0; reg < 4; ++reg) {
        const int row = r0 + reg;
        if (row < NN) {
            g[(size_t)row * 64 + nq * 16 + l15] = f2bf(c0[reg] * dd[reg]);
            g[(size_t)row * 64 + (nq + 1) * 16 + l15] = f2bf(c1[reg] * dd[reg]);
        }
    }
}

// ---------------------------------------------------------------- agg2 + pooling fused (256 thr, 8 lanes/node) + graph counts
__global__ __launch_bounds__(256) void agg_pool(const unsigned short* __restrict__ h,
                                                const int2* __restrict__ row_range,
                                                const int* __restrict__ csr_src,
                                                const float* __restrict__ dis,
                                                const float* __restrict__ bias,
                                                const int* __restrict__ batch,
                                                float* __restrict__ psum,
                                                float* __restrict__ cnt) {
    __shared__ float rowsL[32 * 68];
    __shared__ int nb[32];
    const int t = threadIdx.x;
    const int nloc = t >> 3;
    const int n = blockIdx.x * 32 + nloc;
    const int p8 = (t & 7) * 8;
    if ((t & 7) == 0) nb[nloc] = (n < NN) ? batch[n] : -1;
    if (n < NN) {
        const int2 rr = row_range[n];
        float acc[8] = {};
        gather_rows(h, csr_src, rr.x, rr.y, p8, acc);
        const float dn = dis[n];
        const float4 bv0 = *(const float4*)&bias[p8];
        const float4 bv1 = *(const float4*)&bias[p8 + 4];
        float4 r0, r1;
        r0.x = fmaxf(acc[0] * dn + bv0.x, 0.f);
        r0.y = fmaxf(acc[1] * dn + bv0.y, 0.f);
        r0.z = fmaxf(acc[2] * dn + bv0.z, 0.f);
        r0.w = fmaxf(acc[3] * dn + bv0.w, 0.f);
        r1.x = fmaxf(acc[4] * dn + bv1.x, 0.f);
        r1.y = fmaxf(acc[5] * dn + bv1.y, 0.f);
        r1.z = fmaxf(acc[6] * dn + bv1.z, 0.f);
        r1.w = fmaxf(acc[7] * dn + bv1.w, 0.f);
        *(float4*)&rowsL[nloc * 68 + p8] = r0;
        *(float4*)&rowsL[nloc * 68 + p8 + 4] = r1;
    }
    __syncthreads();
    if (t < 64) {
        float s = 0.f; int curg = -2; int rl = 0;
        for (int r = 0; r < 32; ++r) {
            const int gg = nb[r];                 // wave-uniform
            if (gg != curg) {
                if (curg >= 0) {
                    atomicAdd(&psum[curg * 64 + t], s);
                    if (t == 0) atomicAdd(&cnt[curg], (float)rl);
                }
                s = 0.f; rl = 0; curg = gg;
            }
            if (gg >= 0) { s += rowsL[r * 68 + t]; ++rl; }
        }
        if (curg >= 0) {
            atomicAdd(&psum[curg * 64 + t], s);
            if (t == 0) atomicAdd(&cnt[curg], (float)rl);
        }
    }
}

// ---------------------------------------------------------------- head: mean + MLP (no binary search)
__global__ __launch_bounds__(64) void head_kernel(const float* __restrict__ psum,
                                                  const float* __restrict__ cnt,
                                                  const float* __restrict__ Wm1,
                                                  const float* __restrict__ bm1,
                                                  const float* __restrict__ Wm2,
                                                  const float* __restrict__ bm2,
                                                  float* __restrict__ out) {
    const int g = blockIdx.x;
    const int t = threadIdx.x;
    __shared__ float pl[64];
    const float inv = 1.f / fmaxf(cnt[g], 1.f);
    pl[t] = psum[g * 64 + t] * inv;
    __syncthreads();
    float z = bm1[t];
#pragma unroll 8
    for (int k = 0; k < 64; ++k)
        z += pl[k] * Wm1[k * 64 + t];
    z = fmaxf(z, 0.f);
    float y = z * Wm2[t];
    for (int off = 32; off; off >>= 1) y += __shfl_down(y, off);
    if (t == 0) out[g] = y + bm2[0];
}

// ---------------------------------------------------------------- launch
extern "C" void kernel_launch(void* const* d_in, const int* in_sizes, int n_in,
                              void* d_out, int out_size, void* d_ws, size_t ws_size,
                              hipStream_t stream) {
    const float* x   = (const float*)d_in[0];
    const int*   ei  = (const int*)d_in[1];
    const int*   bat = (const int*)d_in[2];
    const float* W1  = (const float*)d_in[3];
    const float* b1  = (const float*)d_in[4];
    const float* W2  = (const float*)d_in[5];
    const float* b2  = (const float*)d_in[6];
    const float* Wm1 = (const float*)d_in[7];
    const float* bm1 = (const float*)d_in[8];
    const float* Wm2 = (const float*)d_in[9];
    const float* bm2 = (const float*)d_in[10];
    float* out = (float*)d_out;

    char* w = (char*)d_ws;
    int*            histg     = (int*)           (w + 0);          //   153664 B
    int2*           row_range = (int2*)          (w + 153664);     //   400000 B
    float*          dis       = (float*)         (w + 553664);     //   200000 B
    int*            csr_src   = (int*)           (w + 753664);     //  4014080 B
    unsigned*       ebuf      = (unsigned*)      (w + 4767744);    // 12293120 B (packed 4B edges)
    unsigned short* bufA      = (unsigned short*)(w + 17060864);   //  6400000 B
    unsigned short* bufB      = (unsigned short*)(w + 23460864);   //  6400000 B
    float*          psum      = (float*)         (w + 29860864);   //    66560 B (16384 psum + 256 cnt)
    unsigned*       W2p       = (unsigned*)      (w + 29927424);   //     8192 B
    float*          cnt       = psum + 16384;

    prep_gemm <<<NC + NGB + 1, 256, 0, stream>>>(ei, histg, ebuf, x, W1, W2, bufA, psum, W2p);
    build_csr <<<NB, 512, 0, stream>>>(ebuf, histg, row_range, dis, csr_src);
    agg_gemv  <<<(NN + 31) / 32, 256, 0, stream>>>(bufA, row_range, csr_src, dis, b1, W2p, bufB);
    agg_pool  <<<(NN + 31) / 32, 256, 0, stream>>>(bufB, row_range, csr_src, dis, b2, bat, psum, cnt);
    head_kernel<<<NG, 64, 0, stream>>>(psum, cnt, Wm1, bm1, Wm2, bm2, out);
}